// Round 6
// baseline (560.811 us; speedup 1.0000x reference)
//
#include <hip/hip_runtime.h>

#define N_ 32
#define C_ 512
#define T_ 2048
#define K_ 1024
#define NT_ 65536
#define EPS_ 0.12f

typedef _Float16 f16;
typedef f16 f16x2 __attribute__((ext_vector_type(2)));
typedef f16 f16x4 __attribute__((ext_vector_type(4)));
typedef f16 f16x8 __attribute__((ext_vector_type(8)));
typedef float f32x4 __attribute__((ext_vector_type(4)));

// ---- ws layout (bytes) ----
#define OFF_CBH  ((size_t)0)          // f16 cb, tiled [8 kblk][16 co][128 k][32 c]  (1 MB)
#define OFF_KN   ((size_t)1048576)    // fp32 knorm [1024]
#define OFF_CNT  ((size_t)1052672)    // int count (zeroed by knorm_init)
#define OFF_LST  ((size_t)1052928)    // int worklist [65536]
#define WS_NEED  ((size_t)1315072)

#define GLOAD(g, l) __builtin_amdgcn_global_load_lds( \
    (__attribute__((address_space(1))) const unsigned int*)(const void*)(g), \
    (__attribute__((address_space(3))) unsigned int*)(void*)(l), 16, 0, 0)

// ---------------- Kernel 1: codebook norms + zero scalars + zero worklist count ----------------
__global__ void knorm_init_kernel(const float* __restrict__ cb,
                                  float* __restrict__ knorm,
                                  float* __restrict__ out,
                                  int* __restrict__ cnt) {
    const int k = blockIdx.x;
    const int lane = threadIdx.x;
    const float* row = cb + (size_t)k * C_;
    float s = 0.f;
#pragma unroll
    for (int j = 0; j < C_ / 64; ++j) {
        float v = row[lane + 64 * j];
        s += v * v;
    }
#pragma unroll
    for (int off = 32; off > 0; off >>= 1) s += __shfl_down(s, off, 64);
    if (lane == 0) knorm[k] = s;
    if (k == 0 && lane == 0) {
        out[(size_t)N_ * C_ * T_ + 0] = 0.f;
        out[(size_t)N_ * C_ * T_ + 1] = 0.f;
        *cnt = 0;
    }
}

// ---------------- Kernel 2: convert codebook to tiled f16 ----------------
// cb [1024][512] fp32 -> cbws [kblk][co][128 k][32 c] f16;  128 blocks: b>>4=kblk, b&15=co
__global__ void __launch_bounds__(256) conv_cb_kernel(const float* __restrict__ cb,
                                                      f16* __restrict__ cbws) {
    const int tid = threadIdx.x;
    const int kblk = blockIdx.x >> 4;
    const int co = blockIdx.x & 15;
    const float* src = cb + (size_t)kblk * 128 * C_ + co * 32;
    f16* dst = cbws + (size_t)kblk * 65536 + (size_t)co * 4096;
#pragma unroll
    for (int j = 0; j < 4; ++j) {
        int f = tid + 256 * j;            // 0..1023
        int k_l = f >> 3;                 // 0..127
        int c4 = (f & 7) * 4;             // 0..28
        float4 v = *(const float4*)(src + (size_t)k_l * C_ + c4);
        f16x4 h = {(f16)v.x, (f16)v.y, (f16)v.z, (f16)v.w};
        *(f16x4*)(dst + (size_t)k_l * 32 + c4) = h;
    }
}

// ---------------- Kernel 3: FUSED transpose + MFMA full-K top2 + gather ----------------
// 512 blocks (one per 128-t tile) x 512 threads (8 waves: wt 0..3 t-quarter, wk 0..1 k-half).
// Phase A: transpose x fp32 -> f16 A-fragments held in REGISTERS (a[16 co][2 ti], 128 VGPR).
// Phase B: loop kblk 0..7 { 8 double-buffered B-stage phases (verified GLOAD swizzle),
//          16 MFMA/wave/phase, fold per-kblk top2 into running top2 (combine semantics) }.
// Epilogue: worklist append for marginal rows + fused gather-write of out.
__global__ void __launch_bounds__(512, 2)
vq_main_kernel(const float* __restrict__ x, const float* __restrict__ cb,
               const f16* __restrict__ cbws, const float* __restrict__ knorm,
               float* __restrict__ out, int* __restrict__ cnt, int* __restrict__ list) {
    __shared__ __align__(16) char smem[32768];   // B dbuf 2x16KB; transpose scratch uses [0,8KB)
    __shared__ float kns[1024];
    __shared__ float mrg[128 * 2 * 3];
    __shared__ int idxs[128];

    const int tid = threadIdx.x;
    const int lane = tid & 63, w = tid >> 6;      // w 0..7
    const int wt = w >> 1, wk = w & 1;
    const int col = lane & 15, quad = lane >> 4;
    const int b = blockIdx.x;
    const int n = b >> 4;
    const int t0 = (b & 15) << 7;

    kns[tid] = knorm[tid];
    kns[tid + 512] = knorm[tid + 512];

    // ---------- transpose x -> A fragments in registers ----------
    // thread (cp 0..15, s 0..31): loads rows c0=2cp, c0+1 of this co-tile at t=4s..4s+3,
    // writes 4 f16x2 into At[128 t][32 c] (64B rows) with chunk XOR swizzle
    // chunk' = chunk ^ ((t>>2)&3)  (write key (s&3) == ((4s+i)>>2)&3; read key ((t>>2)&3)).
    const int cp = tid >> 5, s = tid & 31;
    const float* xbase = x + ((size_t)n * C_ + cp * 2) * T_ + t0 + s * 4;
    f16x8 a[16][2];
#pragma unroll
    for (int co = 0; co < 16; ++co) {
        __syncthreads();                      // At free (prev co's reads done)
        f32x4 v0 = *(const f32x4*)(xbase + (size_t)(co * 32) * T_);
        f32x4 v1 = *(const f32x4*)(xbase + (size_t)(co * 32 + 1) * T_);
#pragma unroll
        for (int i = 0; i < 4; ++i) {
            int t = s * 4 + i;
            f16x2 h = {(f16)v0[i], (f16)v1[i]};
            *(f16x2*)(smem + t * 64 + (((cp >> 2) ^ (s & 3)) << 4) + ((cp & 3) << 2)) = h;
        }
        __syncthreads();
#pragma unroll
        for (int ti = 0; ti < 2; ++ti) {
            int t = wt * 32 + ti * 16 + col;
            a[co][ti] = *(const f16x8*)(smem + t * 64 + ((quad ^ ((t >> 2) & 3)) << 4));
        }
    }

    // ---------- main loop: 8 kblk x 8 cog double-buffered phases ----------
    // source-side chunk swizzle (verified R3/R4): per-wave 2KB window, 1KB per GLOAD
    const int swz = ((lane >> 2) << 6) + (((lane & 3) ^ ((lane >> 3) & 3)) << 4);
    const char* gB = (const char*)cbws + w * 2048 + swz;
    char* lB = smem + w * 2048;
    const int rchunk = (quad ^ ((col >> 1) & 3)) << 4;

    __syncthreads();                          // transpose reads done; smem now B's
    GLOAD(gB, lB);                            // prologue: stage phase 0 into buf0
    GLOAD(gB + 1024, lB + 1024);
    __syncthreads();                          // phase 0 landed & visible

    float rv1f = 3.4e38f, rv2f = 3.4e38f;     // running top2 (valid in tid<128)
    int ri1f = 0;

    for (int kblk = 0; kblk < 8; ++kblk) {
        f32x4 acc[2][4];
#pragma unroll
        for (int i = 0; i < 2; ++i)
#pragma unroll
            for (int j = 0; j < 4; ++j) acc[i][j] = (f32x4){0.f, 0.f, 0.f, 0.f};
#pragma unroll
        for (int cog = 0; cog < 8; ++cog) {
            const int cur = cog & 1;          // phase parity is static (kblk*8 even)
            const int p1 = kblk * 8 + cog + 1;
            if (p1 < 64) {                    // prefetch next 16KB (2 co-tiles, contiguous)
                const char* gn = (const char*)cbws + (size_t)p1 * 16384 + w * 2048 + swz;
                char* ln = smem + (cur ^ 1) * 16384 + w * 2048;
                GLOAD(gn, ln);
                GLOAD(gn + 1024, ln + 1024);
            }
            const char* Bs = smem + cur * 16384;
#pragma unroll
            for (int co2 = 0; co2 < 2; ++co2) {
                f16x8 bf[4];
#pragma unroll
                for (int ki = 0; ki < 4; ++ki)
                    bf[ki] = *(const f16x8*)(Bs + co2 * 8192 + (wk * 64 + ki * 16 + col) * 64 + rchunk);
#pragma unroll
                for (int ti = 0; ti < 2; ++ti)
#pragma unroll
                    for (int ki = 0; ki < 4; ++ki)
                        acc[ti][ki] = __builtin_amdgcn_mfma_f32_16x16x32_f16(
                            a[cog * 2 + co2][ti], bf[ki], acc[ti][ki], 0, 0, 0);
            }
            __syncthreads();                  // drains prefetch; protects buf reuse
        }
        // ---- fold this kblk's top2 into running (combine semantics) ----
#pragma unroll
        for (int ti = 0; ti < 2; ++ti) {
#pragma unroll
            for (int reg = 0; reg < 4; ++reg) {
                float rv1 = 3.4e38f, rv2 = 3.4e38f;
                int ri1 = 0;
#pragma unroll
                for (int ki = 0; ki < 4; ++ki) {
                    int kl = wk * 64 + ki * 16 + col;
                    float sc = fmaf(-2.f, acc[ti][ki][reg], kns[kblk * 128 + kl]);
                    int kg = kblk * 128 + kl;
                    if (sc < rv1) { rv2 = rv1; rv1 = sc; ri1 = kg; }
                    else if (sc < rv2) rv2 = sc;
                }
#pragma unroll
                for (int m = 1; m <= 8; m <<= 1) {
                    float ov1 = __shfl_xor(rv1, m, 64);
                    float ov2 = __shfl_xor(rv2, m, 64);
                    int oi1 = __shfl_xor(ri1, m, 64);
                    float nv2 = fminf(fminf(rv2, ov2), fmaxf(rv1, ov1));
                    if (ov1 < rv1 || (ov1 == rv1 && oi1 < ri1)) { rv1 = ov1; ri1 = oi1; }
                    rv2 = nv2;
                }
                if (col == 0) {
                    int t_l = wt * 32 + ti * 16 + quad * 4 + reg;
                    float* p = &mrg[(t_l * 2 + wk) * 3];
                    p[0] = rv1; p[1] = __int_as_float(ri1); p[2] = rv2;
                }
            }
        }
        __syncthreads();
        if (tid < 128) {
            const float* pa = &mrg[tid * 6];
            const float* pb = &mrg[tid * 6 + 3];
            float v1 = pa[0], v2 = pa[2];
            int i1 = __float_as_int(pa[1]);
            float ov1 = pb[0], ov2 = pb[2];
            int oi1 = __float_as_int(pb[1]);
            float nv2 = fminf(fminf(v2, ov2), fmaxf(v1, ov1));
            if (ov1 < v1 || (ov1 == v1 && oi1 < i1)) { v1 = ov1; i1 = oi1; }
            // fold (v1,i1,nv2) into running top2
            float fv2 = fminf(fminf(rv2f, nv2), fmaxf(rv1f, v1));
            if (v1 < rv1f || (v1 == rv1f && i1 < ri1f)) { rv1f = v1; ri1f = i1; }
            rv2f = fv2;
        }
        __syncthreads();                      // mrg reuse next kblk
    }

    // ---------- epilogue: worklist + fused gather ----------
    if (tid < 128) {
        if (rv2f <= rv1f + 2.f * EPS_) {
            int p = atomicAdd(cnt, 1);
            list[p] = b * 128 + tid;
        }
        idxs[tid] = ri1f;
    }
    __syncthreads();
    const int tg = (tid & 31) * 4;
    const int cs = tid >> 5;                  // 0..15
    const float* r0 = cb + (size_t)idxs[tg + 0] * C_;
    const float* r1 = cb + (size_t)idxs[tg + 1] * C_;
    const float* r2 = cb + (size_t)idxs[tg + 2] * C_;
    const float* r3 = cb + (size_t)idxs[tg + 3] * C_;
    float* obase = out + (size_t)n * C_ * T_ + t0 + tg;
    for (int c = cs; c < C_; c += 16) {
        float4 v;
        v.x = r0[c]; v.y = r1[c]; v.z = r2[c]; v.w = r3[c];
        *(float4*)&obase[(size_t)c * T_] = v;
    }
}

// ---------------- Kernel 4: exact fp32 rescan + out rewrite ----------------
// Same verified LDS-staged rescan as before; instead of writing idx, it rewrites
// the out rows for its (marginal) worklist items with the exact fp32 winner.
__global__ void __launch_bounds__(256) rescan3b_kernel(const float* __restrict__ x,
                                                       const float* __restrict__ cb,
                                                       const float* __restrict__ knorm,
                                                       const int* __restrict__ cnt,
                                                       const int* __restrict__ list,
                                                       float* __restrict__ out) {
    __shared__ __align__(16) f32x4 tile[4][512];   // 32KB: [c4][code ^ (c4<<1)]
    __shared__ __align__(16) float xs[4][512];     // 8KB
    __shared__ float redv[4][256];                 // 4KB
    __shared__ int redk[4][256];                   // 4KB
    const int tid = threadIdx.x;
    const int nf = *cnt;
    for (int base = blockIdx.x * 4; base < nf; base += gridDim.x * 4) {
        const int nr = (nf - base < 4) ? (nf - base) : 4;
        __syncthreads();   // protect xs/tile/redk reuse across grid-stride iterations
        for (int i = tid; i < nr * 512; i += 256) {
            int r = i >> 9, c = i & 511;
            int rr = list[base + r];
            int n = rr >> 11, t = rr & 2047;
            xs[r][c] = x[(size_t)n * C_ * T_ + (size_t)c * T_ + t];
        }

        float bv[4];
        int bk[4];
#pragma unroll
        for (int r = 0; r < 4; ++r) { bv[r] = 3.4e38f; bk[r] = 0; }

        for (int kpass = 0; kpass < 2; ++kpass) {
            float acc[2][4];   // [j(code)][item]
#pragma unroll
            for (int j = 0; j < 2; ++j)
#pragma unroll
                for (int r = 0; r < 4; ++r) acc[j][r] = 0.f;

            for (int cc = 0; cc < 32; ++cc) {      // 16-float c-chunks
                __syncthreads();
#pragma unroll
                for (int jj = 0; jj < 8; ++jj) {
                    int q = tid + 256 * jj;        // 0..2047
                    int row = q >> 2;              // 0..511
                    int c4 = q & 3;                // 0..3
                    f32x4 v = *(const f32x4*)(cb + (size_t)(kpass * 512 + row) * C_ + cc * 16 + c4 * 4);
                    tile[c4][row ^ (c4 << 1)] = v;
                }
                __syncthreads();
                f32x4 xv[4][4];
#pragma unroll
                for (int r = 0; r < 4; ++r)
#pragma unroll
                    for (int c4 = 0; c4 < 4; ++c4)
                        xv[r][c4] = *(const f32x4*)&xs[r][cc * 16 + c4 * 4];
#pragma unroll
                for (int j = 0; j < 2; ++j) {
                    int kl = tid + 256 * j;
#pragma unroll
                    for (int c4 = 0; c4 < 4; ++c4) {
                        f32x4 cv = tile[c4][kl ^ (c4 << 1)];
#pragma unroll
                        for (int r = 0; r < 4; ++r) {
                            acc[j][r] = fmaf(cv.x, xv[r][c4].x, acc[j][r]);
                            acc[j][r] = fmaf(cv.y, xv[r][c4].y, acc[j][r]);
                            acc[j][r] = fmaf(cv.z, xv[r][c4].z, acc[j][r]);
                            acc[j][r] = fmaf(cv.w, xv[r][c4].w, acc[j][r]);
                        }
                    }
                }
            }
#pragma unroll
            for (int j = 0; j < 2; ++j) {
                int k = kpass * 512 + tid + 256 * j;
                float kn = knorm[k];
#pragma unroll
                for (int r = 0; r < 4; ++r) {
                    float sc = fmaf(-2.f, acc[j][r], kn);
                    if (sc < bv[r]) { bv[r] = sc; bk[r] = k; }
                }
            }
        }
#pragma unroll
        for (int r = 0; r < 4; ++r) {
            redv[r][tid] = bv[r];
            redk[r][tid] = bk[r];
        }
        __syncthreads();
        for (int off = 128; off > 0; off >>= 1) {
            if (tid < off) {
#pragma unroll
                for (int r = 0; r < 4; ++r) {
                    float ov = redv[r][tid + off];
                    int ok = redk[r][tid + off];
                    if (ov < redv[r][tid] || (ov == redv[r][tid] && ok < redk[r][tid])) {
                        redv[r][tid] = ov;
                        redk[r][tid] = ok;
                    }
                }
            }
            __syncthreads();
        }
        // rewrite out rows with the exact winner (overwrites vq_main's approx row)
        for (int i = tid; i < nr * 512; i += 256) {
            int r = i >> 9, c = i & 511;
            int rr = list[base + r];
            int n = rr >> 11, t = rr & 2047;
            out[(size_t)n * C_ * T_ + (size_t)c * T_ + t] = cb[(size_t)redk[r][0] * C_ + c];
        }
    }
}

// ---------------- Fallback (round-1 fp32 path, verified correct) ----------------
__global__ void __launch_bounds__(256)
vq_fallback_kernel(const float* __restrict__ x, const float* __restrict__ cb,
                   const float* __restrict__ knorm, float* __restrict__ out) {
    __shared__ float smem[4416];
    float* Xs = smem;
    float* Bs = smem + 2048;
    float* kns = smem + 4160;
    int* idxs = (int*)(smem + 4288);
    float* redv = smem;
    int* redk = (int*)(smem + 2048);

    const int tid = threadIdx.x;
    const int tx = tid & 15;
    const int ty = tid >> 4;
    const int b = blockIdx.x;
    const int n = b >> 4;
    const int t0 = (b & 15) * 128;
    const float* xbase = x + (size_t)n * C_ * T_ + t0;

    float best[8];
    int bestk[8];
#pragma unroll
    for (int i = 0; i < 8; ++i) { best[i] = 3.4e38f; bestk[i] = 0; }

    for (int k0 = 0; k0 < K_; k0 += 128) {
        if (tid < 128) kns[tid] = knorm[k0 + tid];
        float acc[8][8];
#pragma unroll
        for (int i = 0; i < 8; ++i)
#pragma unroll
            for (int j = 0; j < 8; ++j) acc[i][j] = 0.f;
        for (int cc = 0; cc < C_; cc += 16) {
            __syncthreads();
#pragma unroll
            for (int j = 0; j < 2; ++j) {
                int f = tid + 256 * j;
                int cl = f >> 5;
                int t4 = (f & 31) * 4;
                float4 v = *(const float4*)(xbase + (size_t)(cc + cl) * T_ + t4);
                *(float4*)&Xs[cl * 128 + t4] = v;
            }
#pragma unroll
            for (int j = 0; j < 2; ++j) {
                int f = tid + 256 * j;
                int kl = f >> 2;
                int c4 = (f & 3) * 4;
                float4 v = *(const float4*)(cb + (size_t)(k0 + kl) * C_ + cc + c4);
                Bs[(c4 + 0) * 132 + kl] = v.x;
                Bs[(c4 + 1) * 132 + kl] = v.y;
                Bs[(c4 + 2) * 132 + kl] = v.z;
                Bs[(c4 + 3) * 132 + kl] = v.w;
            }
            __syncthreads();
#pragma unroll
            for (int c = 0; c < 16; ++c) {
                float4 xa = *(const float4*)&Xs[c * 128 + ty * 8];
                float4 xb2 = *(const float4*)&Xs[c * 128 + ty * 8 + 4];
                float4 ba = *(const float4*)&Bs[c * 132 + tx * 8];
                float4 bb = *(const float4*)&Bs[c * 132 + tx * 8 + 4];
                float xr[8] = {xa.x, xa.y, xa.z, xa.w, xb2.x, xb2.y, xb2.z, xb2.w};
                float br[8] = {ba.x, ba.y, ba.z, ba.w, bb.x, bb.y, bb.z, bb.w};
#pragma unroll
                for (int i = 0; i < 8; ++i)
#pragma unroll
                    for (int j = 0; j < 8; ++j)
                        acc[i][j] = fmaf(xr[i], br[j], acc[i][j]);
            }
        }
#pragma unroll
        for (int j = 0; j < 8; ++j) {
            const int kk = k0 + tx * 8 + j;
            const float kn = kns[tx * 8 + j];
#pragma unroll
            for (int i = 0; i < 8; ++i) {
                float s = fmaf(-2.f, acc[i][j], kn);
                if (s < best[i]) { best[i] = s; bestk[i] = kk; }
            }
        }
        __syncthreads();
    }
#pragma unroll
    for (int i = 0; i < 8; ++i) {
        redv[(ty * 8 + i) * 16 + tx] = best[i];
        redk[(ty * 8 + i) * 16 + tx] = bestk[i];
    }
    __syncthreads();
    if (tid < 128) {
        float bv = redv[tid * 16];
        int bk = redk[tid * 16];
#pragma unroll
        for (int j = 1; j < 16; ++j) {
            float v = redv[tid * 16 + j];
            int kj = redk[tid * 16 + j];
            if (v < bv || (v == bv && kj < bk)) { bv = v; bk = kj; }
        }
        idxs[tid] = bk;
    }
    __syncthreads();
    const int tg = (tid & 31) * 4;
    const int cs = tid >> 5;
    const float* r0 = cb + (size_t)idxs[tg + 0] * C_;
    const float* r1 = cb + (size_t)idxs[tg + 1] * C_;
    const float* r2 = cb + (size_t)idxs[tg + 2] * C_;
    const float* r3 = cb + (size_t)idxs[tg + 3] * C_;
    float* obase = out + (size_t)n * C_ * T_ + t0 + tg;
    for (int c = cs; c < C_; c += 8) {
        float4 v;
        v.x = r0[c]; v.y = r1[c]; v.z = r2[c]; v.w = r3[c];
        *(float4*)&obase[(size_t)c * T_] = v;
    }
}

extern "C" void kernel_launch(void* const* d_in, const int* in_sizes, int n_in,
                              void* d_out, int out_size, void* d_ws, size_t ws_size,
                              hipStream_t stream) {
    const float* x = (const float*)d_in[0];    // [32,512,2048] fp32
    const float* cb = (const float*)d_in[1];   // [1024,512] fp32
    float* out = (float*)d_out;
    char* ws = (char*)d_ws;

    if (ws_size < WS_NEED) {
        float* kn = (float*)ws;
        int* cnt0 = (int*)(ws + 4096);
        knorm_init_kernel<<<K_, 64, 0, stream>>>(cb, kn, out, cnt0);
        vq_fallback_kernel<<<(NT_) / 128, 256, 0, stream>>>(x, cb, kn, out);
        return;
    }

    f16* cbws = (f16*)(ws + OFF_CBH);
    float* knorm = (float*)(ws + OFF_KN);
    int* cnt = (int*)(ws + OFF_CNT);
    int* list = (int*)(ws + OFF_LST);

    knorm_init_kernel<<<K_, 64, 0, stream>>>(cb, knorm, out, cnt);
    conv_cb_kernel<<<128, 256, 0, stream>>>(cb, cbws);
    vq_main_kernel<<<512, 512, 0, stream>>>(x, cb, cbws, knorm, out, cnt, list);
    rescan3b_kernel<<<512, 256, 0, stream>>>(x, cb, knorm, cnt, list, out);
}